// Round 1
// baseline (242.991 us; speedup 1.0000x reference)
//
#include <hip/hip_runtime.h>

typedef __bf16 bf16x8 __attribute__((ext_vector_type(8)));
typedef float f32x4 __attribute__((ext_vector_type(4)));

#define BS 4096
#define D 1024
#define M2 8192

#define BM 128
#define BN 128
#define BK 32

// workspace layout (bytes)
#define OFF_Z      ((size_t)0)
#define OFF_SUMEXP ((size_t)M2 * D * 2)          // 16 MiB of bf16 Z
#define OFF_POS    (OFF_SUMEXP + (size_t)M2 * 4)
#define OFF_DIO    (OFF_POS + (size_t)M2 * 4)
#define OFF_DJO    (OFF_DIO + (size_t)BS * 4)

static __device__ __forceinline__ unsigned short f2bf(float x) {
  union { float f; unsigned int u; } c; c.f = x;
  unsigned int u = c.u;
  return (unsigned short)((u + 0x7FFFu + ((u >> 16) & 1u)) >> 16);
}

static __device__ __forceinline__ void gload_lds16(const void* g, void* l) {
  __builtin_amdgcn_global_load_lds(
      (__attribute__((address_space(1))) void*)(uintptr_t)g,
      (__attribute__((address_space(3))) void*)(unsigned int)(uintptr_t)l,
      16, 0, 0);
}

// ---------------- kernel 1: normalize rows, emit bf16 Z, per-row dots ----------------
__global__ __launch_bounds__(256) void prep_kernel(
    const float* __restrict__ zi, const float* __restrict__ zj,
    const float* __restrict__ zo, unsigned short* __restrict__ Z,
    float* __restrict__ dio, float* __restrict__ djo) {
  const int r = blockIdx.x;
  const int tid = threadIdx.x;
  const float4 vi = ((const float4*)(zi + (size_t)r * D))[tid];
  const float4 vj = ((const float4*)(zj + (size_t)r * D))[tid];
  const float4 vo = ((const float4*)(zo + (size_t)r * D))[tid];

  float s[5];
  s[0] = vi.x * vi.x + vi.y * vi.y + vi.z * vi.z + vi.w * vi.w;
  s[1] = vj.x * vj.x + vj.y * vj.y + vj.z * vj.z + vj.w * vj.w;
  s[2] = vo.x * vo.x + vo.y * vo.y + vo.z * vo.z + vo.w * vo.w;
  s[3] = vi.x * vo.x + vi.y * vo.y + vi.z * vo.z + vi.w * vo.w;
  s[4] = vj.x * vo.x + vj.y * vo.y + vj.z * vo.z + vj.w * vo.w;

#pragma unroll
  for (int k = 0; k < 5; ++k)
#pragma unroll
    for (int o = 32; o; o >>= 1) s[k] += __shfl_xor(s[k], o);

  __shared__ float red[4][5];
  const int w = tid >> 6, lane = tid & 63;
  if (lane == 0) {
#pragma unroll
    for (int k = 0; k < 5; ++k) red[w][k] = s[k];
  }
  __syncthreads();
  float tot[5];
#pragma unroll
  for (int k = 0; k < 5; ++k)
    tot[k] = red[0][k] + red[1][k] + red[2][k] + red[3][k];

  const float rsi = 1.0f / sqrtf(tot[0]);
  const float rsj = 1.0f / sqrtf(tot[1]);
  const float rso = 1.0f / sqrtf(tot[2]);

  ushort4 oi, oj;
  oi.x = f2bf(vi.x * rsi); oi.y = f2bf(vi.y * rsi);
  oi.z = f2bf(vi.z * rsi); oi.w = f2bf(vi.w * rsi);
  oj.x = f2bf(vj.x * rsj); oj.y = f2bf(vj.y * rsj);
  oj.z = f2bf(vj.z * rsj); oj.w = f2bf(vj.w * rsj);
  ((ushort4*)(Z + (size_t)r * D))[tid] = oi;
  ((ushort4*)(Z + (size_t)(BS + r) * D))[tid] = oj;

  if (tid == 0) {
    dio[r] = tot[3] * rsi * rso;
    djo[r] = tot[4] * rsj * rso;
  }
}

// ---------------- kernel 2: S = Z Z^T tile, fused exp/row-sum/pos epilogue ----------------
__global__ __launch_bounds__(256) void gemm_lse_kernel(
    const unsigned short* __restrict__ Z,
    float* __restrict__ sumexp, float* __restrict__ pos) {
  __shared__ __align__(16) __bf16 lA[BM * BK];
  __shared__ __align__(16) __bf16 lB[BN * BK];
  __shared__ float psum[2][BM];

  const int tid = threadIdx.x;
  const int bn = blockIdx.x, bm = blockIdx.y;
  const int lane = tid & 63, w = tid >> 6;
  const int wr = w >> 1, wc = w & 1;
  const int lr = lane & 15, lg = lane >> 4;

  const unsigned short* gA = Z + (size_t)(bm * BM + (tid >> 2)) * D + (tid & 3) * 8;
  const unsigned short* gB = Z + (size_t)(bn * BN + (tid >> 2)) * D + (tid & 3) * 8;
  __bf16* lAp = &lA[tid * 8];
  __bf16* lBp = &lB[tid * 8];

  f32x4 acc[4][4] = {};

  for (int kt = 0; kt < D; kt += BK) {
    gload_lds16(gA, lAp);
    gload_lds16(gA + (size_t)64 * D, lAp + 64 * BK);
    gload_lds16(gB, lBp);
    gload_lds16(gB + (size_t)64 * D, lBp + 64 * BK);
    gA += BK; gB += BK;
    __syncthreads();

    bf16x8 af[4], bfr[4];
#pragma unroll
    for (int m = 0; m < 4; ++m)
      af[m] = *(const bf16x8*)&lA[(wr * 64 + m * 16 + lr) * BK + lg * 8];
#pragma unroll
    for (int n = 0; n < 4; ++n)
      bfr[n] = *(const bf16x8*)&lB[(wc * 64 + n * 16 + lr) * BK + lg * 8];

#pragma unroll
    for (int m = 0; m < 4; ++m)
#pragma unroll
      for (int n = 0; n < 4; ++n)
        acc[m][n] = __builtin_amdgcn_mfma_f32_16x16x32_bf16(af[m], bfr[n], acc[m][n], 0, 0, 0);
    __syncthreads();
  }

  // epilogue: exp + diag-exclusion + pos capture + row partial sums
  const int gr0 = bm * BM + wr * 64;
  const int gc0 = bn * BN + wc * 64;
#pragma unroll
  for (int m = 0; m < 4; ++m) {
#pragma unroll
    for (int j = 0; j < 4; ++j) {
      const int gq = gr0 + m * 16 + lg * 4 + j;
      const int prt = gq ^ BS;
      float sse = 0.f;
#pragma unroll
      for (int n = 0; n < 4; ++n) {
        const int gc = gc0 + n * 16 + lr;
        const float v = acc[m][n][j];
        if (gc == prt) pos[gq] = v;
        if (gc != gq) sse += __expf(v);
      }
      sse += __shfl_xor(sse, 1);
      sse += __shfl_xor(sse, 2);
      sse += __shfl_xor(sse, 4);
      sse += __shfl_xor(sse, 8);
      if (lr == 0) psum[wc][wr * 64 + m * 16 + lg * 4 + j] = sse;
    }
  }
  __syncthreads();
  if (tid < BM) atomicAdd(&sumexp[bm * BM + tid], psum[0][tid] + psum[1][tid]);
}

// ---------------- kernel 3: final reduction + KL ----------------
__global__ __launch_bounds__(256) void finalize_kernel(
    const float* __restrict__ sumexp, const float* __restrict__ pos,
    const float* __restrict__ dio, const float* __restrict__ djo,
    float* __restrict__ out) {
  const int tid = threadIdx.x;
  float s1 = 0.f, sa = 0.f, sb = 0.f;
  for (int q = tid; q < M2; q += 256) s1 += __logf(sumexp[q]) - pos[q];
  for (int r = tid; r < BS; r += 256) { sa += __expf(dio[r]); sb += __expf(djo[r]); }

  __shared__ float red[4][3];
  float v3[3] = {s1, sa, sb};
#pragma unroll
  for (int k = 0; k < 3; ++k)
#pragma unroll
    for (int o = 32; o; o >>= 1) v3[k] += __shfl_xor(v3[k], o);
  const int w = tid >> 6, lane = tid & 63;
  if (lane == 0) { red[w][0] = v3[0]; red[w][1] = v3[1]; red[w][2] = v3[2]; }
  __syncthreads();
  const float S1 = red[0][0] + red[1][0] + red[2][0] + red[3][0];
  const float A  = red[0][1] + red[1][1] + red[2][1] + red[3][1];
  const float B  = red[0][2] + red[1][2] + red[2][2] + red[3][2];
  const float logB = __logf(B);
  const float invA = 1.0f / A;

  float kl = 0.f;
  for (int r = tid; r < BS; r += 256) {
    const float lp = djo[r] - logB;            // log_softmax target
    kl += __expf(lp) * (lp - __expf(dio[r]) * invA);
  }
#pragma unroll
  for (int o = 32; o; o >>= 1) kl += __shfl_xor(kl, o);
  __shared__ float red2[4];
  if (lane == 0) red2[w] = kl;
  __syncthreads();
  if (tid == 0) {
    const float KL = red2[0] + red2[1] + red2[2] + red2[3];
    out[0] = S1 / (float)M2 + 0.5f * KL;
  }
}

extern "C" void kernel_launch(void* const* d_in, const int* in_sizes, int n_in,
                              void* d_out, int out_size, void* d_ws, size_t ws_size,
                              hipStream_t stream) {
  const float* zi = (const float*)d_in[0];
  const float* zj = (const float*)d_in[1];
  const float* zo = (const float*)d_in[2];
  char* ws = (char*)d_ws;
  unsigned short* Z = (unsigned short*)(ws + OFF_Z);
  float* sumexp = (float*)(ws + OFF_SUMEXP);
  float* pos    = (float*)(ws + OFF_POS);
  float* dio    = (float*)(ws + OFF_DIO);
  float* djo    = (float*)(ws + OFF_DJO);

  hipMemsetAsync(sumexp, 0, (size_t)M2 * sizeof(float), stream);
  prep_kernel<<<BS, 256, 0, stream>>>(zi, zj, zo, Z, dio, djo);
  gemm_lse_kernel<<<dim3(M2 / BN, M2 / BM), 256, 0, stream>>>(Z, sumexp, pos);
  finalize_kernel<<<1, 256, 0, stream>>>(sumexp, pos, dio, djo, (float*)d_out);
}

// Round 2
// 171.738 us; speedup vs baseline: 1.4149x; 1.4149x over previous
//
#include <hip/hip_runtime.h>

typedef __bf16 bf16x8 __attribute__((ext_vector_type(8)));
typedef float f32x4 __attribute__((ext_vector_type(4)));

#define BS 4096
#define D 1024
#define M2 8192

#define BM 128
#define BN 128
#define BK 32
#define NT 64            // M2/BM tiles per dim
#define NBLK (NT * (NT + 1) / 2)   // 2080 upper-triangle blocks

// workspace layout (bytes)
#define OFF_Z      ((size_t)0)
#define OFF_SUMEXP ((size_t)M2 * D * 2)          // 16 MiB of bf16 Z
#define OFF_POS    (OFF_SUMEXP + (size_t)M2 * 4)
#define OFF_DIO    (OFF_POS + (size_t)M2 * 4)
#define OFF_DJO    (OFF_DIO + (size_t)BS * 4)

static __device__ __forceinline__ unsigned short f2bf(float x) {
  union { float f; unsigned int u; } c; c.f = x;
  unsigned int u = c.u;
  return (unsigned short)((u + 0x7FFFu + ((u >> 16) & 1u)) >> 16);
}

static __device__ __forceinline__ void gload_lds16(const void* g, void* l) {
  __builtin_amdgcn_global_load_lds(
      (__attribute__((address_space(1))) void*)(uintptr_t)g,
      (__attribute__((address_space(3))) void*)(unsigned int)(uintptr_t)l,
      16, 0, 0);
}

// ---------------- kernel 1: normalize rows, emit bf16 Z, per-row dots ----------------
__global__ __launch_bounds__(256) void prep_kernel(
    const float* __restrict__ zi, const float* __restrict__ zj,
    const float* __restrict__ zo, unsigned short* __restrict__ Z,
    float* __restrict__ dio, float* __restrict__ djo) {
  const int r = blockIdx.x;
  const int tid = threadIdx.x;
  const float4 vi = ((const float4*)(zi + (size_t)r * D))[tid];
  const float4 vj = ((const float4*)(zj + (size_t)r * D))[tid];
  const float4 vo = ((const float4*)(zo + (size_t)r * D))[tid];

  float s[5];
  s[0] = vi.x * vi.x + vi.y * vi.y + vi.z * vi.z + vi.w * vi.w;
  s[1] = vj.x * vj.x + vj.y * vj.y + vj.z * vj.z + vj.w * vj.w;
  s[2] = vo.x * vo.x + vo.y * vo.y + vo.z * vo.z + vo.w * vo.w;
  s[3] = vi.x * vo.x + vi.y * vo.y + vi.z * vo.z + vi.w * vo.w;
  s[4] = vj.x * vo.x + vj.y * vo.y + vj.z * vo.z + vj.w * vo.w;

#pragma unroll
  for (int k = 0; k < 5; ++k)
#pragma unroll
    for (int o = 32; o; o >>= 1) s[k] += __shfl_xor(s[k], o);

  __shared__ float red[4][5];
  const int w = tid >> 6, lane = tid & 63;
  if (lane == 0) {
#pragma unroll
    for (int k = 0; k < 5; ++k) red[w][k] = s[k];
  }
  __syncthreads();
  float tot[5];
#pragma unroll
  for (int k = 0; k < 5; ++k)
    tot[k] = red[0][k] + red[1][k] + red[2][k] + red[3][k];

  const float rsi = 1.0f / sqrtf(tot[0]);
  const float rsj = 1.0f / sqrtf(tot[1]);
  const float rso = 1.0f / sqrtf(tot[2]);

  ushort4 oi, oj;
  oi.x = f2bf(vi.x * rsi); oi.y = f2bf(vi.y * rsi);
  oi.z = f2bf(vi.z * rsi); oi.w = f2bf(vi.w * rsi);
  oj.x = f2bf(vj.x * rsj); oj.y = f2bf(vj.y * rsj);
  oj.z = f2bf(vj.z * rsj); oj.w = f2bf(vj.w * rsj);
  ((ushort4*)(Z + (size_t)r * D))[tid] = oi;
  ((ushort4*)(Z + (size_t)(BS + r) * D))[tid] = oj;

  if (tid == 0) {
    dio[r] = tot[3] * rsi * rso;
    djo[r] = tot[4] * rsj * rso;
  }
}

// ---------------- kernel 2: upper-triangle S = Z Z^T, fused exp/row+col-sum/pos ----------------
__global__ __launch_bounds__(256) void gemm_lse_kernel(
    const unsigned short* __restrict__ Z,
    float* __restrict__ sumexp, float* __restrict__ pos) {
  __shared__ __align__(16) __bf16 lA[BM * BK];
  __shared__ __align__(16) __bf16 lB[BN * BK];
  __shared__ float psumR[2][BM];
  __shared__ float psumC[2][BN];

  // triangular decode: block t -> (bm, bn) with bm <= bn
  const int t = blockIdx.x;
  int bm = (int)((129.0f - sqrtf(16641.0f - 8.0f * (float)t)) * 0.5f);
  while ((bm + 1) * (129 - (bm + 1)) / 2 <= t) ++bm;
  while (bm * (129 - bm) / 2 > t) --bm;
  const int bn = bm + (t - bm * (129 - bm) / 2);
  const bool isDiag = (bm == bn);

  const int tid = threadIdx.x;
  const int lane = tid & 63, w = tid >> 6;
  const int wr = w >> 1, wc = w & 1;
  const int lr = lane & 15, lg = lane >> 4;

  const unsigned short* gA = Z + (size_t)(bm * BM + (tid >> 2)) * D + (tid & 3) * 8;
  const unsigned short* gB = Z + (size_t)(bn * BN + (tid >> 2)) * D + (tid & 3) * 8;
  __bf16* lAp = &lA[tid * 8];
  __bf16* lBp = &lB[tid * 8];

  f32x4 acc[4][4] = {};

  for (int kt = 0; kt < D; kt += BK) {
    gload_lds16(gA, lAp);
    gload_lds16(gA + (size_t)64 * D, lAp + 64 * BK);
    gload_lds16(gB, lBp);
    gload_lds16(gB + (size_t)64 * D, lBp + 64 * BK);
    gA += BK; gB += BK;
    __syncthreads();

    bf16x8 af[4], bfr[4];
#pragma unroll
    for (int m = 0; m < 4; ++m)
      af[m] = *(const bf16x8*)&lA[(wr * 64 + m * 16 + lr) * BK + lg * 8];
#pragma unroll
    for (int n = 0; n < 4; ++n)
      bfr[n] = *(const bf16x8*)&lB[(wc * 64 + n * 16 + lr) * BK + lg * 8];

#pragma unroll
    for (int m = 0; m < 4; ++m)
#pragma unroll
      for (int n = 0; n < 4; ++n)
        acc[m][n] = __builtin_amdgcn_mfma_f32_16x16x32_bf16(af[m], bfr[n], acc[m][n], 0, 0, 0);
    __syncthreads();
  }

  // epilogue: exp once per value; row sums always; col sums for off-diag (mirror rows)
  const int gr0 = bm * BM + wr * 64;
  const int gc0 = bn * BN + wc * 64;
  float csum[4] = {0.f, 0.f, 0.f, 0.f};
#pragma unroll
  for (int m = 0; m < 4; ++m) {
#pragma unroll
    for (int j = 0; j < 4; ++j) {
      const int gq = gr0 + m * 16 + lg * 4 + j;
      const int prt = gq ^ BS;
      float sse = 0.f;
#pragma unroll
      for (int n = 0; n < 4; ++n) {
        const int gc = gc0 + n * 16 + lr;
        const float v = acc[m][n][j];
        if (gc == prt) { pos[gq] = v; pos[gc] = v; }   // symmetric pair
        const float e = (gc != gq) ? __expf(v) : 0.f;  // diag self-term excluded
        sse += e;
        csum[n] += e;
      }
      sse += __shfl_xor(sse, 1);
      sse += __shfl_xor(sse, 2);
      sse += __shfl_xor(sse, 4);
      sse += __shfl_xor(sse, 8);
      if (lr == 0) psumR[wc][wr * 64 + m * 16 + lg * 4 + j] = sse;
    }
  }
  if (!isDiag) {
#pragma unroll
    for (int n = 0; n < 4; ++n) {
      csum[n] += __shfl_xor(csum[n], 16);
      csum[n] += __shfl_xor(csum[n], 32);
      if (lg == 0) psumC[wr][wc * 64 + n * 16 + lr] = csum[n];
    }
  }
  __syncthreads();
  if (tid < BM) atomicAdd(&sumexp[bm * BM + tid], psumR[0][tid] + psumR[1][tid]);
  if (!isDiag && tid < BN)
    atomicAdd(&sumexp[bn * BN + tid], psumC[0][tid] + psumC[1][tid]);
}

// ---------------- kernel 3: final reduction + KL ----------------
__global__ __launch_bounds__(256) void finalize_kernel(
    const float* __restrict__ sumexp, const float* __restrict__ pos,
    const float* __restrict__ dio, const float* __restrict__ djo,
    float* __restrict__ out) {
  const int tid = threadIdx.x;
  float s1 = 0.f, sa = 0.f, sb = 0.f;
  for (int q = tid; q < M2; q += 256) s1 += __logf(sumexp[q]) - pos[q];
  for (int r = tid; r < BS; r += 256) { sa += __expf(dio[r]); sb += __expf(djo[r]); }

  __shared__ float red[4][3];
  float v3[3] = {s1, sa, sb};
#pragma unroll
  for (int k = 0; k < 3; ++k)
#pragma unroll
    for (int o = 32; o; o >>= 1) v3[k] += __shfl_xor(v3[k], o);
  const int w = tid >> 6, lane = tid & 63;
  if (lane == 0) { red[w][0] = v3[0]; red[w][1] = v3[1]; red[w][2] = v3[2]; }
  __syncthreads();
  const float S1 = red[0][0] + red[1][0] + red[2][0] + red[3][0];
  const float A  = red[0][1] + red[1][1] + red[2][1] + red[3][1];
  const float B  = red[0][2] + red[1][2] + red[2][2] + red[3][2];
  const float logB = __logf(B);
  const float invA = 1.0f / A;

  float kl = 0.f;
  for (int r = tid; r < BS; r += 256) {
    const float lp = djo[r] - logB;            // log_softmax target
    kl += __expf(lp) * (lp - __expf(dio[r]) * invA);
  }
#pragma unroll
  for (int o = 32; o; o >>= 1) kl += __shfl_xor(kl, o);
  __shared__ float red2[4];
  if (lane == 0) red2[w] = kl;
  __syncthreads();
  if (tid == 0) {
    const float KL = red2[0] + red2[1] + red2[2] + red2[3];
    out[0] = S1 / (float)M2 + 0.5f * KL;
  }
}

extern "C" void kernel_launch(void* const* d_in, const int* in_sizes, int n_in,
                              void* d_out, int out_size, void* d_ws, size_t ws_size,
                              hipStream_t stream) {
  const float* zi = (const float*)d_in[0];
  const float* zj = (const float*)d_in[1];
  const float* zo = (const float*)d_in[2];
  char* ws = (char*)d_ws;
  unsigned short* Z = (unsigned short*)(ws + OFF_Z);
  float* sumexp = (float*)(ws + OFF_SUMEXP);
  float* pos    = (float*)(ws + OFF_POS);
  float* dio    = (float*)(ws + OFF_DIO);
  float* djo    = (float*)(ws + OFF_DJO);

  hipMemsetAsync(sumexp, 0, (size_t)M2 * sizeof(float), stream);
  prep_kernel<<<BS, 256, 0, stream>>>(zi, zj, zo, Z, dio, djo);
  gemm_lse_kernel<<<NBLK, 256, 0, stream>>>(Z, sumexp, pos);
  finalize_kernel<<<1, 256, 0, stream>>>(sumexp, pos, dio, djo, (float*)d_out);
}

// Round 3
// 147.842 us; speedup vs baseline: 1.6436x; 1.1616x over previous
//
#include <hip/hip_runtime.h>

typedef __bf16 bf16x8 __attribute__((ext_vector_type(8)));
typedef float f32x4 __attribute__((ext_vector_type(4)));

#define BS 4096
#define D 1024
#define M2 8192

#define BM 128
#define BN 128
#define BK 32
#define NKT (D / BK)     // 32 K-steps
#define NT 64            // M2/BM tiles per dim
#define NBLK (NT * (NT + 1) / 2)   // 2080 upper-triangle blocks (2080 % 8 == 0)

// workspace layout (bytes)
#define OFF_Z      ((size_t)0)
#define OFF_SUMEXP ((size_t)M2 * D * 2)          // 16 MiB of bf16 Z
#define OFF_POS    (OFF_SUMEXP + (size_t)M2 * 4)
#define OFF_DIO    (OFF_POS + (size_t)M2 * 4)
#define OFF_DJO    (OFF_DIO + (size_t)BS * 4)

static __device__ __forceinline__ unsigned short f2bf(float x) {
  union { float f; unsigned int u; } c; c.f = x;
  unsigned int u = c.u;
  return (unsigned short)((u + 0x7FFFu + ((u >> 16) & 1u)) >> 16);
}

static __device__ __forceinline__ void gload_lds16(const void* g, void* l) {
  __builtin_amdgcn_global_load_lds(
      (__attribute__((address_space(1))) void*)(uintptr_t)g,
      (__attribute__((address_space(3))) void*)(unsigned int)(uintptr_t)l,
      16, 0, 0);
}

// ---------------- kernel 1: normalize rows, emit bf16 Z, per-row dots ----------------
__global__ __launch_bounds__(256) void prep_kernel(
    const float* __restrict__ zi, const float* __restrict__ zj,
    const float* __restrict__ zo, unsigned short* __restrict__ Z,
    float* __restrict__ dio, float* __restrict__ djo) {
  const int r = blockIdx.x;
  const int tid = threadIdx.x;
  const float4 vi = ((const float4*)(zi + (size_t)r * D))[tid];
  const float4 vj = ((const float4*)(zj + (size_t)r * D))[tid];
  const float4 vo = ((const float4*)(zo + (size_t)r * D))[tid];

  float s[5];
  s[0] = vi.x * vi.x + vi.y * vi.y + vi.z * vi.z + vi.w * vi.w;
  s[1] = vj.x * vj.x + vj.y * vj.y + vj.z * vj.z + vj.w * vj.w;
  s[2] = vo.x * vo.x + vo.y * vo.y + vo.z * vo.z + vo.w * vo.w;
  s[3] = vi.x * vo.x + vi.y * vo.y + vi.z * vo.z + vi.w * vo.w;
  s[4] = vj.x * vo.x + vj.y * vo.y + vj.z * vo.z + vj.w * vo.w;

#pragma unroll
  for (int k = 0; k < 5; ++k)
#pragma unroll
    for (int o = 32; o; o >>= 1) s[k] += __shfl_xor(s[k], o);

  __shared__ float red[4][5];
  const int w = tid >> 6, lane = tid & 63;
  if (lane == 0) {
#pragma unroll
    for (int k = 0; k < 5; ++k) red[w][k] = s[k];
  }
  __syncthreads();
  float tot[5];
#pragma unroll
  for (int k = 0; k < 5; ++k)
    tot[k] = red[0][k] + red[1][k] + red[2][k] + red[3][k];

  const float rsi = 1.0f / sqrtf(tot[0]);
  const float rsj = 1.0f / sqrtf(tot[1]);
  const float rso = 1.0f / sqrtf(tot[2]);

  ushort4 oi, oj;
  oi.x = f2bf(vi.x * rsi); oi.y = f2bf(vi.y * rsi);
  oi.z = f2bf(vi.z * rsi); oi.w = f2bf(vi.w * rsi);
  oj.x = f2bf(vj.x * rsj); oj.y = f2bf(vj.y * rsj);
  oj.z = f2bf(vj.z * rsj); oj.w = f2bf(vj.w * rsj);
  ((ushort4*)(Z + (size_t)r * D))[tid] = oi;
  ((ushort4*)(Z + (size_t)(BS + r) * D))[tid] = oj;

  if (tid == 0) {
    dio[r] = tot[3] * rsi * rso;
    djo[r] = tot[4] * rsj * rso;
  }
}

// ---------------- kernel 2: upper-triangle S = Z Z^T, pipelined, fused epilogue ----------------
__global__ __launch_bounds__(256) void gemm_lse_kernel(
    const unsigned short* __restrict__ Z,
    float* __restrict__ sumexp, float* __restrict__ pos) {
  __shared__ __align__(16) __bf16 lA[2][BM * BK];
  __shared__ __align__(16) __bf16 lB[2][BN * BK];
  __shared__ float psumR[2][BM];
  __shared__ float psumC[2][BN];

  // XCD-bijective swizzle (2080 = 8 * 260): each XCD gets a contiguous run
  const int torig = blockIdx.x;
  const int t = (torig & 7) * (NBLK / 8) + (torig >> 3);

  // triangular decode: block t -> (bm, bn) with bm <= bn
  int bm = (int)((129.0f - sqrtf(16641.0f - 8.0f * (float)t)) * 0.5f);
  while ((bm + 1) * (129 - (bm + 1)) / 2 <= t) ++bm;
  while (bm * (129 - bm) / 2 > t) --bm;
  const int bn = bm + (t - bm * (129 - bm) / 2);
  const bool isDiag = (bm == bn);

  const int tid = threadIdx.x;
  const int lane = tid & 63, w = tid >> 6;
  const int wr = w >> 1, wc = w & 1;
  const int lr = lane & 15, lg = lane >> 4;

  const unsigned short* gA = Z + (size_t)(bm * BM + (tid >> 2)) * D + (tid & 3) * 8;
  const unsigned short* gB = Z + (size_t)(bn * BN + (tid >> 2)) * D + (tid & 3) * 8;

#define STAGE(buf)                                              \
  do {                                                          \
    gload_lds16(gA, &lA[buf][tid * 8]);                         \
    gload_lds16(gA + (size_t)64 * D, &lA[buf][tid * 8 + 64 * BK]); \
    gload_lds16(gB, &lB[buf][tid * 8]);                         \
    gload_lds16(gB + (size_t)64 * D, &lB[buf][tid * 8 + 64 * BK]); \
    gA += BK; gB += BK;                                         \
  } while (0)

  f32x4 acc[4][4] = {};

  STAGE(0);  // prologue: 4 loads in flight for k-tile 0

  for (int kt = 0; kt < NKT; ++kt) {
    const int cur = kt & 1;
    if (kt < NKT - 1) {
      STAGE(cur ^ 1);                       // issue next-tile loads (stay in flight)
      asm volatile("s_waitcnt vmcnt(4)");   // wait only for cur-tile's 4 loads
    } else {
      asm volatile("s_waitcnt vmcnt(0)");
    }
    __builtin_amdgcn_s_barrier();           // everyone's cur-tile data visible
    __builtin_amdgcn_sched_barrier(0);      // pin: no ds_read hoisted above barrier

    bf16x8 af[4], bfr[4];
#pragma unroll
    for (int m = 0; m < 4; ++m)
      af[m] = *(const bf16x8*)&lA[cur][(wr * 64 + m * 16 + lr) * BK + lg * 8];
#pragma unroll
    for (int n = 0; n < 4; ++n)
      bfr[n] = *(const bf16x8*)&lB[cur][(wc * 64 + n * 16 + lr) * BK + lg * 8];

#pragma unroll
    for (int m = 0; m < 4; ++m)
#pragma unroll
      for (int n = 0; n < 4; ++n)
        acc[m][n] = __builtin_amdgcn_mfma_f32_16x16x32_bf16(af[m], bfr[n], acc[m][n], 0, 0, 0);

    __builtin_amdgcn_sched_barrier(0);
    __builtin_amdgcn_s_barrier();           // all waves done reading buf[cur]
  }
#undef STAGE

  // epilogue: exp once per value; row sums always; col sums for off-diag (mirror rows)
  const int gr0 = bm * BM + wr * 64;
  const int gc0 = bn * BN + wc * 64;
  float csum[4] = {0.f, 0.f, 0.f, 0.f};
#pragma unroll
  for (int m = 0; m < 4; ++m) {
#pragma unroll
    for (int j = 0; j < 4; ++j) {
      const int gq = gr0 + m * 16 + lg * 4 + j;
      const int prt = gq ^ BS;
      float sse = 0.f;
#pragma unroll
      for (int n = 0; n < 4; ++n) {
        const int gc = gc0 + n * 16 + lr;
        const float v = acc[m][n][j];
        if (gc == prt) { pos[gq] = v; pos[gc] = v; }   // symmetric pair
        const float e = (gc != gq) ? __expf(v) : 0.f;  // diag self-term excluded
        sse += e;
        csum[n] += e;
      }
      sse += __shfl_xor(sse, 1);
      sse += __shfl_xor(sse, 2);
      sse += __shfl_xor(sse, 4);
      sse += __shfl_xor(sse, 8);
      if (lr == 0) psumR[wc][wr * 64 + m * 16 + lg * 4 + j] = sse;
    }
  }
  if (!isDiag) {
#pragma unroll
    for (int n = 0; n < 4; ++n) {
      csum[n] += __shfl_xor(csum[n], 16);
      csum[n] += __shfl_xor(csum[n], 32);
      if (lg == 0) psumC[wr][wc * 64 + n * 16 + lr] = csum[n];
    }
  }
  __syncthreads();
  if (tid < BM) atomicAdd(&sumexp[bm * BM + tid], psumR[0][tid] + psumR[1][tid]);
  if (!isDiag && tid < BN)
    atomicAdd(&sumexp[bn * BN + tid], psumC[0][tid] + psumC[1][tid]);
}

// ---------------- kernel 3: final reduction + KL ----------------
__global__ __launch_bounds__(256) void finalize_kernel(
    const float* __restrict__ sumexp, const float* __restrict__ pos,
    const float* __restrict__ dio, const float* __restrict__ djo,
    float* __restrict__ out) {
  const int tid = threadIdx.x;
  float s1 = 0.f, sa = 0.f, sb = 0.f;
  for (int q = tid; q < M2; q += 256) s1 += __logf(sumexp[q]) - pos[q];
  for (int r = tid; r < BS; r += 256) { sa += __expf(dio[r]); sb += __expf(djo[r]); }

  __shared__ float red[4][3];
  float v3[3] = {s1, sa, sb};
#pragma unroll
  for (int k = 0; k < 3; ++k)
#pragma unroll
    for (int o = 32; o; o >>= 1) v3[k] += __shfl_xor(v3[k], o);
  const int w = tid >> 6, lane = tid & 63;
  if (lane == 0) { red[w][0] = v3[0]; red[w][1] = v3[1]; red[w][2] = v3[2]; }
  __syncthreads();
  const float S1 = red[0][0] + red[1][0] + red[2][0] + red[3][0];
  const float A  = red[0][1] + red[1][1] + red[2][1] + red[3][1];
  const float B  = red[0][2] + red[1][2] + red[2][2] + red[3][2];
  const float logB = __logf(B);
  const float invA = 1.0f / A;

  float kl = 0.f;
  for (int r = tid; r < BS; r += 256) {
    const float lp = djo[r] - logB;            // log_softmax target
    kl += __expf(lp) * (lp - __expf(dio[r]) * invA);
  }
#pragma unroll
  for (int o = 32; o; o >>= 1) kl += __shfl_xor(kl, o);
  __shared__ float red2[4];
  if (lane == 0) red2[w] = kl;
  __syncthreads();
  if (tid == 0) {
    const float KL = red2[0] + red2[1] + red2[2] + red2[3];
    out[0] = S1 / (float)M2 + 0.5f * KL;
  }
}

extern "C" void kernel_launch(void* const* d_in, const int* in_sizes, int n_in,
                              void* d_out, int out_size, void* d_ws, size_t ws_size,
                              hipStream_t stream) {
  const float* zi = (const float*)d_in[0];
  const float* zj = (const float*)d_in[1];
  const float* zo = (const float*)d_in[2];
  char* ws = (char*)d_ws;
  unsigned short* Z = (unsigned short*)(ws + OFF_Z);
  float* sumexp = (float*)(ws + OFF_SUMEXP);
  float* pos    = (float*)(ws + OFF_POS);
  float* dio    = (float*)(ws + OFF_DIO);
  float* djo    = (float*)(ws + OFF_DJO);

  hipMemsetAsync(sumexp, 0, (size_t)M2 * sizeof(float), stream);
  prep_kernel<<<BS, 256, 0, stream>>>(zi, zj, zo, Z, dio, djo);
  gemm_lse_kernel<<<NBLK, 256, 0, stream>>>(Z, sumexp, pos);
  finalize_kernel<<<1, 256, 0, stream>>>(sumexp, pos, dio, djo, (float*)d_out);
}

// Round 4
// 130.726 us; speedup vs baseline: 1.8588x; 1.1309x over previous
//
#include <hip/hip_runtime.h>

typedef __bf16 bf16x8 __attribute__((ext_vector_type(8)));
typedef float f32x4 __attribute__((ext_vector_type(4)));

#define BS 4096
#define D 1024
#define M2 8192

#define BM 128
#define BN 128
#define BK 32
#define NKT (D / BK)     // 32 K-steps
#define NT 64            // M2/BM tiles per dim
#define NBLK (NT * (NT + 1) / 2)   // 2080 upper-triangle blocks (2080 % 8 == 0)

// workspace layout (bytes)
#define OFF_Z      ((size_t)0)
#define OFF_SUMEXP ((size_t)M2 * D * 2)          // 16 MiB of bf16 Z
#define OFF_POS    (OFF_SUMEXP + (size_t)M2 * 4)
#define OFF_DIO    (OFF_POS + (size_t)M2 * 4)
#define OFF_DJO    (OFF_DIO + (size_t)BS * 4)

static __device__ __forceinline__ unsigned short f2bf(float x) {
  union { float f; unsigned int u; } c; c.f = x;
  unsigned int u = c.u;
  return (unsigned short)((u + 0x7FFFu + ((u >> 16) & 1u)) >> 16);
}

static __device__ __forceinline__ void gload_lds16(const void* g, void* l) {
  __builtin_amdgcn_global_load_lds(
      (__attribute__((address_space(1))) void*)(uintptr_t)g,
      (__attribute__((address_space(3))) void*)(unsigned int)(uintptr_t)l,
      16, 0, 0);
}

// ---------------- kernel 1: normalize rows, emit bf16 Z, per-row dots ----------------
__global__ __launch_bounds__(256) void prep_kernel(
    const float* __restrict__ zi, const float* __restrict__ zj,
    const float* __restrict__ zo, unsigned short* __restrict__ Z,
    float* __restrict__ dio, float* __restrict__ djo) {
  const int r = blockIdx.x;
  const int tid = threadIdx.x;
  const float4 vi = ((const float4*)(zi + (size_t)r * D))[tid];
  const float4 vj = ((const float4*)(zj + (size_t)r * D))[tid];
  const float4 vo = ((const float4*)(zo + (size_t)r * D))[tid];

  float s[5];
  s[0] = vi.x * vi.x + vi.y * vi.y + vi.z * vi.z + vi.w * vi.w;
  s[1] = vj.x * vj.x + vj.y * vj.y + vj.z * vj.z + vj.w * vj.w;
  s[2] = vo.x * vo.x + vo.y * vo.y + vo.z * vo.z + vo.w * vo.w;
  s[3] = vi.x * vo.x + vi.y * vo.y + vi.z * vo.z + vi.w * vo.w;
  s[4] = vj.x * vo.x + vj.y * vo.y + vj.z * vo.z + vj.w * vo.w;

#pragma unroll
  for (int k = 0; k < 5; ++k)
#pragma unroll
    for (int o = 32; o; o >>= 1) s[k] += __shfl_xor(s[k], o);

  __shared__ float red[4][5];
  const int w = tid >> 6, lane = tid & 63;
  if (lane == 0) {
#pragma unroll
    for (int k = 0; k < 5; ++k) red[w][k] = s[k];
  }
  __syncthreads();
  float tot[5];
#pragma unroll
  for (int k = 0; k < 5; ++k)
    tot[k] = red[0][k] + red[1][k] + red[2][k] + red[3][k];

  const float rsi = 1.0f / sqrtf(tot[0]);
  const float rsj = 1.0f / sqrtf(tot[1]);
  const float rso = 1.0f / sqrtf(tot[2]);

  ushort4 oi, oj;
  oi.x = f2bf(vi.x * rsi); oi.y = f2bf(vi.y * rsi);
  oi.z = f2bf(vi.z * rsi); oi.w = f2bf(vi.w * rsi);
  oj.x = f2bf(vj.x * rsj); oj.y = f2bf(vj.y * rsj);
  oj.z = f2bf(vj.z * rsj); oj.w = f2bf(vj.w * rsj);
  ((ushort4*)(Z + (size_t)r * D))[tid] = oi;
  ((ushort4*)(Z + (size_t)(BS + r) * D))[tid] = oj;

  if (tid == 0) {
    dio[r] = tot[3] * rsi * rso;
    djo[r] = tot[4] * rsj * rso;
  }
}

// ---------------- kernel 2: upper-triangle S = Z Z^T, depth-2 pipeline, fused epilogue ----------------
__global__ __launch_bounds__(256) void gemm_lse_kernel(
    const unsigned short* __restrict__ Z,
    float* __restrict__ sumexp, float* __restrict__ pos) {
  __shared__ __align__(16) __bf16 lA[3][BM * BK];
  __shared__ __align__(16) __bf16 lB[3][BN * BK];
  __shared__ float psumR[2][BM];
  __shared__ float psumC[2][BN];

  // XCD-bijective swizzle (2080 = 8 * 260): each XCD gets a contiguous run
  const int torig = blockIdx.x;
  const int t = (torig & 7) * (NBLK / 8) + (torig >> 3);

  // triangular decode: block t -> (bm, bn) with bm <= bn
  int bm = (int)((129.0f - sqrtf(16641.0f - 8.0f * (float)t)) * 0.5f);
  while ((bm + 1) * (129 - (bm + 1)) / 2 <= t) ++bm;
  while (bm * (129 - bm) / 2 > t) --bm;
  const int bn = bm + (t - bm * (129 - bm) / 2);
  const bool isDiag = (bm == bn);

  const int tid = threadIdx.x;
  const int lane = tid & 63, w = tid >> 6;
  const int wr = w >> 1, wc = w & 1;
  const int lr = lane & 15, lg = lane >> 4;

  // staging: thread tid owns LDS chunk tid (rows 0-63) and tid+256 (rows 64-127).
  // XOR-swizzle: LDS chunk (row, c) holds global chunk c ^ (row & 3).
  // (row+64 has the same row&3, so one source offset serves both halves.)
  const int srow = tid >> 2;
  const int schunk = (tid & 3) ^ (srow & 3);
  const unsigned short* gA = Z + (size_t)(bm * BM + srow) * D + schunk * 8;
  const unsigned short* gB = Z + (size_t)(bn * BN + srow) * D + schunk * 8;

#define STAGE(buf)                                                 \
  do {                                                             \
    gload_lds16(gA, &lA[buf][tid * 8]);                            \
    gload_lds16(gA + (size_t)64 * D, &lA[buf][tid * 8 + 64 * BK]); \
    gload_lds16(gB, &lB[buf][tid * 8]);                            \
    gload_lds16(gB + (size_t)64 * D, &lB[buf][tid * 8 + 64 * BK]); \
    gA += BK; gB += BK;                                            \
  } while (0)

  f32x4 acc[4][4] = {};

  STAGE(0);  // tile 0 in flight (4 loads)
  STAGE(1);  // tile 1 in flight (8 outstanding)

  // read-side swizzled chunk offset: row&3 == lr&3 for all fragments
  const int swz = (lg ^ (lr & 3)) * 8;

  for (int kt = 0; kt < NKT; ++kt) {
    const int cur = kt % 3;
    if (kt < NKT - 2) {
      STAGE((kt + 2) % 3);                  // 12 outstanding; keep 8 in flight
      asm volatile("s_waitcnt vmcnt(8)");   // tile-kt's 4 loads complete
    } else if (kt == NKT - 2) {
      asm volatile("s_waitcnt vmcnt(4)");
    } else {
      asm volatile("s_waitcnt vmcnt(0)");
    }
    __builtin_amdgcn_s_barrier();           // everyone's cur-tile data visible
    __builtin_amdgcn_sched_barrier(0);      // pin: no ds_read hoisted above barrier

    bf16x8 af[4], bfr[4];
#pragma unroll
    for (int m = 0; m < 4; ++m)
      af[m] = *(const bf16x8*)&lA[cur][(wr * 64 + m * 16 + lr) * BK + swz];
#pragma unroll
    for (int n = 0; n < 4; ++n)
      bfr[n] = *(const bf16x8*)&lB[cur][(wc * 64 + n * 16 + lr) * BK + swz];

#pragma unroll
    for (int m = 0; m < 4; ++m)
#pragma unroll
      for (int n = 0; n < 4; ++n)
        acc[m][n] = __builtin_amdgcn_mfma_f32_16x16x32_bf16(af[m], bfr[n], acc[m][n], 0, 0, 0);

    __builtin_amdgcn_sched_barrier(0);
    __builtin_amdgcn_s_barrier();           // all waves done reading buf[cur] -> safe to restage
  }
#undef STAGE

  // epilogue: exp once per value; row sums always; col sums for off-diag (mirror rows)
  const int gr0 = bm * BM + wr * 64;
  const int gc0 = bn * BN + wc * 64;
  float csum[4] = {0.f, 0.f, 0.f, 0.f};
#pragma unroll
  for (int m = 0; m < 4; ++m) {
#pragma unroll
    for (int j = 0; j < 4; ++j) {
      const int gq = gr0 + m * 16 + lg * 4 + j;
      const int prt = gq ^ BS;
      float sse = 0.f;
#pragma unroll
      for (int n = 0; n < 4; ++n) {
        const int gc = gc0 + n * 16 + lr;
        const float v = acc[m][n][j];
        if (gc == prt) { pos[gq] = v; pos[gc] = v; }   // symmetric pair
        const float e = (gc != gq) ? __expf(v) : 0.f;  // diag self-term excluded
        sse += e;
        csum[n] += e;
      }
      sse += __shfl_xor(sse, 1);
      sse += __shfl_xor(sse, 2);
      sse += __shfl_xor(sse, 4);
      sse += __shfl_xor(sse, 8);
      if (lr == 0) psumR[wc][wr * 64 + m * 16 + lg * 4 + j] = sse;
    }
  }
  if (!isDiag) {
#pragma unroll
    for (int n = 0; n < 4; ++n) {
      csum[n] += __shfl_xor(csum[n], 16);
      csum[n] += __shfl_xor(csum[n], 32);
      if (lg == 0) psumC[wr][wc * 64 + n * 16 + lr] = csum[n];
    }
  }
  __syncthreads();
  if (tid < BM) atomicAdd(&sumexp[bm * BM + tid], psumR[0][tid] + psumR[1][tid]);
  if (!isDiag && tid < BN)
    atomicAdd(&sumexp[bn * BN + tid], psumC[0][tid] + psumC[1][tid]);
}

// ---------------- kernel 3: final reduction + KL ----------------
__global__ __launch_bounds__(256) void finalize_kernel(
    const float* __restrict__ sumexp, const float* __restrict__ pos,
    const float* __restrict__ dio, const float* __restrict__ djo,
    float* __restrict__ out) {
  const int tid = threadIdx.x;
  float s1 = 0.f, sa = 0.f, sb = 0.f;
  for (int q = tid; q < M2; q += 256) s1 += __logf(sumexp[q]) - pos[q];
  for (int r = tid; r < BS; r += 256) { sa += __expf(dio[r]); sb += __expf(djo[r]); }

  __shared__ float red[4][3];
  float v3[3] = {s1, sa, sb};
#pragma unroll
  for (int k = 0; k < 3; ++k)
#pragma unroll
    for (int o = 32; o; o >>= 1) v3[k] += __shfl_xor(v3[k], o);
  const int w = tid >> 6, lane = tid & 63;
  if (lane == 0) { red[w][0] = v3[0]; red[w][1] = v3[1]; red[w][2] = v3[2]; }
  __syncthreads();
  const float S1 = red[0][0] + red[1][0] + red[2][0] + red[3][0];
  const float A  = red[0][1] + red[1][1] + red[2][1] + red[3][1];
  const float B  = red[0][2] + red[1][2] + red[2][2] + red[3][2];
  const float logB = __logf(B);
  const float invA = 1.0f / A;

  float kl = 0.f;
  for (int r = tid; r < BS; r += 256) {
    const float lp = djo[r] - logB;            // log_softmax target
    kl += __expf(lp) * (lp - __expf(dio[r]) * invA);
  }
#pragma unroll
  for (int o = 32; o; o >>= 1) kl += __shfl_xor(kl, o);
  __shared__ float red2[4];
  if (lane == 0) red2[w] = kl;
  __syncthreads();
  if (tid == 0) {
    const float KL = red2[0] + red2[1] + red2[2] + red2[3];
    out[0] = S1 / (float)M2 + 0.5f * KL;
  }
}

extern "C" void kernel_launch(void* const* d_in, const int* in_sizes, int n_in,
                              void* d_out, int out_size, void* d_ws, size_t ws_size,
                              hipStream_t stream) {
  const float* zi = (const float*)d_in[0];
  const float* zj = (const float*)d_in[1];
  const float* zo = (const float*)d_in[2];
  char* ws = (char*)d_ws;
  unsigned short* Z = (unsigned short*)(ws + OFF_Z);
  float* sumexp = (float*)(ws + OFF_SUMEXP);
  float* pos    = (float*)(ws + OFF_POS);
  float* dio    = (float*)(ws + OFF_DIO);
  float* djo    = (float*)(ws + OFF_DJO);

  hipMemsetAsync(sumexp, 0, (size_t)M2 * sizeof(float), stream);
  prep_kernel<<<BS, 256, 0, stream>>>(zi, zj, zo, Z, dio, djo);
  gemm_lse_kernel<<<NBLK, 256, 0, stream>>>(Z, sumexp, pos);
  finalize_kernel<<<1, 256, 0, stream>>>(sumexp, pos, dio, djo, (float*)d_out);
}